// Round 1
// baseline (932.916 us; speedup 1.0000x reference)
//
#include <hip/hip_runtime.h>
#include <math.h>

// N=16384, D=64, C=64.
// loss = 1 - (1/n_unique) * sum_c [ (||S_c||^2 - n_c) / (n_c (n_c - 1)) ]
// where S_c = sum of row-normalized features of class c.

#define NCLS 64
#define DIM 64
#define ROWS_PER_BLOCK 256
#define DPAD (DIM + 1)

__global__ __launch_bounds__(256) void cpl_phase1(
    const float* __restrict__ feat,   // [n, DIM]
    const int* __restrict__ pred,     // [n]
    float* __restrict__ partial,      // [nblocks, NCLS*DIM]
    float* __restrict__ cnt_partial,  // [nblocks, NCLS]
    int n)
{
    __shared__ float s_acc[NCLS * DIM];
    __shared__ float s_cnt[NCLS];
    const int tid = threadIdx.x;

    for (int i = tid; i < NCLS * DIM; i += 256) s_acc[i] = 0.0f;
    if (tid < NCLS) s_cnt[tid] = 0.0f;
    __syncthreads();

    const int lane = tid & 63;
    const int wave = tid >> 6;
    const int row0 = blockIdx.x * ROWS_PER_BLOCK + wave * 64;
    const int rowend = row0 + 64;

    for (int r = row0; r < rowend; ++r) {
        if (r >= n) break;
        float x = feat[r * DIM + lane];      // coalesced: lane d -> element d
        float s = x * x;
        #pragma unroll
        for (int off = 32; off; off >>= 1) s += __shfl_xor(s, off, 64);
        float v = x / sqrtf(s);              // row-normalized component
        int c = pred[r];                     // wave-uniform broadcast load
        atomicAdd(&s_acc[c * DIM + lane], v);
        if (lane == 0) atomicAdd(&s_cnt[c], 1.0f);
    }
    __syncthreads();

    float* p = partial + (size_t)blockIdx.x * (NCLS * DIM);
    for (int i = tid; i < NCLS * DIM; i += 256) p[i] = s_acc[i];
    if (tid < NCLS) cnt_partial[blockIdx.x * NCLS + tid] = s_cnt[tid];
}

__global__ __launch_bounds__(64) void cpl_phase2(
    const float* __restrict__ partial,     // [nblocks, NCLS*DIM]
    const float* __restrict__ cnt_partial, // [nblocks, NCLS]
    float* __restrict__ out,               // [1]
    int nblocks)
{
    __shared__ float s_tot[NCLS * DPAD];   // +1 pad: kill stride-64 bank conflict
    const int lane = threadIdx.x;          // 0..63, single wave

    // Reduce per-block partial sums -> total class vectors.
    for (int idx = lane; idx < NCLS * DIM; idx += 64) {
        float s = 0.0f;
        for (int b = 0; b < nblocks; ++b)
            s += partial[(size_t)b * (NCLS * DIM) + idx];
        s_tot[(idx / DIM) * DPAD + (idx % DIM)] = s;
    }
    float cnt = 0.0f;
    for (int b = 0; b < nblocks; ++b) cnt += cnt_partial[b * NCLS + lane];
    __syncthreads();

    // lane = class: ||S_c||^2
    float nsq = 0.0f;
    #pragma unroll
    for (int d = 0; d < DIM; ++d) {
        float t = s_tot[lane * DPAD + d];
        nsq += t * t;
    }
    // avg cos-sim over the n_c-choose-2 pairs; classes with <2 samples -> 0
    float avg = (cnt > 1.5f) ? (nsq - cnt) / (cnt * (cnt - 1.0f)) : 0.0f;
    float present = (cnt > 0.5f) ? 1.0f : 0.0f;
    #pragma unroll
    for (int off = 32; off; off >>= 1) {
        avg     += __shfl_xor(avg, off, 64);
        present += __shfl_xor(present, off, 64);
    }
    if (lane == 0) out[0] = 1.0f - avg / present;
}

extern "C" void kernel_launch(void* const* d_in, const int* in_sizes, int n_in,
                              void* d_out, int out_size, void* d_ws, size_t ws_size,
                              hipStream_t stream) {
    const float* feat = (const float*)d_in[0];
    const int*   pred = (const int*)d_in[1];
    float* out = (float*)d_out;

    const int n = in_sizes[1];                    // 16384 rows
    const int nblocks = (n + ROWS_PER_BLOCK - 1) / ROWS_PER_BLOCK;  // 64

    float* ws = (float*)d_ws;
    float* partial     = ws;                              // nblocks * 4096 floats
    float* cnt_partial = ws + (size_t)nblocks * (NCLS * DIM);  // nblocks * 64 floats

    cpl_phase1<<<nblocks, 256, 0, stream>>>(feat, pred, partial, cnt_partial, n);
    cpl_phase2<<<1, 64, 0, stream>>>(partial, cnt_partial, out, nblocks);
}

// Round 2
// 40.295 us; speedup vs baseline: 23.1521x; 23.1521x over previous
//
#include <hip/hip_runtime.h>
#include <math.h>

// N=16384, D=64, C=64.
// loss = 1 - (1/n_unique) * sum_c [ (||S_c||^2 - n_c) / (n_c (n_c - 1)) ]
// where S_c = sum of row-normalized features of class c.
//
// ws layout: acc[NCLS*DIM] fp32, cnt[NCLS] fp32. Zeroed each call (harness
// does not re-poison between graph replays).

#define NCLS 64
#define DIM 64
#define ROWS_PER_BLOCK 256
#define P1_THREADS 1024
#define ACC_FLOATS (NCLS * DIM + NCLS)

__global__ __launch_bounds__(256) void cpl_zero(float* __restrict__ acc) {
    int i = threadIdx.x + blockIdx.x * 256;
    if (i < ACC_FLOATS) acc[i] = 0.0f;
}

__global__ __launch_bounds__(P1_THREADS) void cpl_phase1(
    const float* __restrict__ feat,   // [n, DIM]
    const int* __restrict__ pred,     // [n]
    float* __restrict__ acc,          // [NCLS*DIM] global accumulator
    float* __restrict__ cnt,          // [NCLS]
    int n)
{
    __shared__ float s_acc[NCLS * DIM];
    __shared__ float s_cnt[NCLS];
    const int tid = threadIdx.x;

    for (int i = tid; i < NCLS * DIM; i += P1_THREADS) s_acc[i] = 0.0f;
    if (tid < NCLS) s_cnt[tid] = 0.0f;
    __syncthreads();

    const int lane = tid & 63;
    const int wave = tid >> 6;                         // 0..15
    const int rows_per_wave = ROWS_PER_BLOCK / (P1_THREADS / 64);  // 16
    const int row0 = blockIdx.x * ROWS_PER_BLOCK + wave * rows_per_wave;

    for (int r = row0; r < row0 + rows_per_wave; ++r) {
        if (r >= n) break;
        float x = feat[(size_t)r * DIM + lane];        // coalesced: lane d
        float s = x * x;
        #pragma unroll
        for (int off = 32; off; off >>= 1) s += __shfl_xor(s, off, 64);
        float v = x / sqrtf(s);                        // normalized component
        int c = pred[r];                               // wave-uniform
        atomicAdd(&s_acc[c * DIM + lane], v);
        if (lane == 0) atomicAdd(&s_cnt[c], 1.0f);
    }
    __syncthreads();

    // Flush block-local sums to the global accumulator (device-scope atomics).
    for (int i = tid; i < NCLS * DIM; i += P1_THREADS) {
        float v = s_acc[i];
        if (v != 0.0f) atomicAdd(&acc[i], v);
    }
    if (tid < NCLS) {
        float v = s_cnt[tid];
        if (v != 0.0f) atomicAdd(&cnt[tid], v);
    }
}

__global__ __launch_bounds__(256) void cpl_finish(
    const float* __restrict__ acc,   // [NCLS*DIM]
    const float* __restrict__ cnt,   // [NCLS]
    float* __restrict__ out)         // [1]
{
    __shared__ float s_avg[NCLS];
    __shared__ float s_pres[NCLS];
    const int t = threadIdx.x;
    const int c = t >> 2;            // 4 threads per class
    const int part = t & 3;

    float s = 0.0f;
    #pragma unroll
    for (int k = 0; k < 16; ++k) {
        float v = acc[c * DIM + part * 16 + k];
        s += v * v;
    }
    // reduce the 4 partials of each class (lanes c*4..c*4+3 are contiguous)
    s += __shfl_xor(s, 1, 64);
    s += __shfl_xor(s, 2, 64);
    if (part == 0) {
        float nc = cnt[c];
        s_avg[c]  = (nc > 1.5f) ? (s - nc) / (nc * (nc - 1.0f)) : 0.0f;
        s_pres[c] = (nc > 0.5f) ? 1.0f : 0.0f;
    }
    __syncthreads();
    if (t < 64) {
        float a = s_avg[t];
        float p = s_pres[t];
        #pragma unroll
        for (int off = 32; off; off >>= 1) {
            a += __shfl_xor(a, off, 64);
            p += __shfl_xor(p, off, 64);
        }
        if (t == 0) out[0] = 1.0f - a / p;
    }
}

extern "C" void kernel_launch(void* const* d_in, const int* in_sizes, int n_in,
                              void* d_out, int out_size, void* d_ws, size_t ws_size,
                              hipStream_t stream) {
    const float* feat = (const float*)d_in[0];
    const int*   pred = (const int*)d_in[1];
    float* out = (float*)d_out;

    const int n = in_sizes[1];                                   // 16384
    const int nblocks = (n + ROWS_PER_BLOCK - 1) / ROWS_PER_BLOCK;  // 64

    float* acc = (float*)d_ws;                 // NCLS*DIM
    float* cnt = acc + NCLS * DIM;             // NCLS

    cpl_zero<<<(ACC_FLOATS + 255) / 256, 256, 0, stream>>>(acc);
    cpl_phase1<<<nblocks, P1_THREADS, 0, stream>>>(feat, pred, acc, cnt, n);
    cpl_finish<<<1, 256, 0, stream>>>(acc, cnt, out);
}